// Round 1
// baseline (23404.541 us; speedup 1.0000x reference)
//
#include <hip/hip_runtime.h>

// 2-layer LSTM, H=256, B=512, T=512, D_IN=1, fused both layers + FC.
// Design: 32 blocks x 1024 threads (16 waves). Each block owns 16 batch rows
// and the FULL gate dimension (sync-free). All recurrent weights live in
// registers as f16 MFMA B-fragments (96 frags = 384 VGPR/lane). h0/h1 are
// double-buffered f16 in LDS, stored in MFMA-fragment element order with an
// XOR bank swizzle so each A-fragment is one ds_read_b128. c-state, biases,
// accumulation and pointwise math are fp32. Input projection (D_IN=1) is a
// rank-1 update folded into accumulator init.

#define Hdim 256
#define Bdim 512
#define Tdim 512
#define NB 16      // batch rows per block
#define NWAVES 16

typedef float f32x4 __attribute__((ext_vector_type(4)));
typedef _Float16 f16x8 __attribute__((ext_vector_type(8)));

__device__ __forceinline__ float sigm(float x){ return 1.0f/(1.0f + __expf(-x)); }
// overflow-safe tanh (c can grow large over 512 steps)
__device__ __forceinline__ float tanh_fast(float x){
  float ax = fabsf(x);
  float e = __expf(-2.0f*ax);
  float r = (1.0f - e)/(1.0f + e);
  return copysignf(r, x);
}

// h LDS layout: per row r, columns stored in MFMA-fragment order:
// pcol(k) groups the 8 elems of fragment (kc,g) contiguously.
__device__ __forceinline__ int pcol(int k){
  return (k&3) | (((k>>4)&1)<<2) | (((k>>2)&3)<<3) | ((k>>5)<<5);
}
// scalar store index (row r, logical col k), with XOR bank swizzle
__device__ __forceinline__ int sidx(int r, int k){
  return r*Hdim + (pcol(k) ^ ((r&7)<<3));
}
// fragment load index (A-row p, K-chunk kc, lane group g): 8 contiguous elems
__device__ __forceinline__ int fidx(int p, int kc, int g){
  return p*Hdim + ((32*kc + 8*g) ^ ((p&7)<<3));
}

// load one B-fragment: elems j=0..3 at k0.., j=4..7 at k0+16..
__device__ __forceinline__ f16x8 load_wfrag(const float* Wrow, int k0){
  float4 a = *(const float4*)(Wrow + k0);
  float4 b = *(const float4*)(Wrow + k0 + 16);
  f16x8 r;
  r[0]=(_Float16)a.x; r[1]=(_Float16)a.y; r[2]=(_Float16)a.z; r[3]=(_Float16)a.w;
  r[4]=(_Float16)b.x; r[5]=(_Float16)b.y; r[6]=(_Float16)b.z; r[7]=(_Float16)b.w;
  return r;
}

__global__ __launch_bounds__(1024, 1) void lstm2_fused(
    const float* __restrict__ x,
    const float* __restrict__ Wih0, const float* __restrict__ Whh0,
    const float* __restrict__ bih0, const float* __restrict__ bhh0,
    const float* __restrict__ Wih1, const float* __restrict__ Whh1,
    const float* __restrict__ bih1, const float* __restrict__ bhh1,
    const float* __restrict__ Wfc,  const float* __restrict__ bfc,
    float* __restrict__ out)
{
  __shared__ float xs[NB][Tdim];            // 32 KB: this block's x rows
  __shared__ _Float16 h0s[2*NB*Hdim];       // 16 KB: layer-1 h, double buffered
  __shared__ _Float16 h1s[2*NB*Hdim];       // 16 KB: layer-2 h, double buffered
  __shared__ float outh[NB][Hdim];          // 16 KB: final h2 in fp32 for FC

  const int tid = threadIdx.x;
  const int w = tid >> 6;      // wave 0..15: owns h-cols [16w,16w+16)
  const int L = tid & 63;
  const int p = L & 15;        // A-row / B-col / C-col within tile
  const int g = L >> 4;        // lane k-group 0..3
  const int R0 = blockIdx.x * NB;
  const int gc1 = 16*w + p;    // this lane's h-column

  // stage x[R0..R0+15][0..511] into LDS (coalesced float4)
  for (int i = tid; i < NB*Tdim/4; i += 1024){
    int r = (4*i) >> 9;
    int cc = (4*i) & (Tdim-1);
    *(float4*)&xs[r][cc] = *(const float4*)&x[(size_t)(R0+r)*Tdim + cc];
  }
  // zero initial hidden state (both buffers, cheap)
  for (int i = tid; i < 2*NB*Hdim; i += 1024){
    h0s[i] = (_Float16)0.0f;
    h1s[i] = (_Float16)0.0f;
  }

  // ---- weights into registers: 3 matrices x 4 gate-tiles x 8 K-chunks
  f16x8 W1[4][8], W2i[4][8], W2h[4][8];
  float bs1[4], wx0v[4], bs2[4];
#pragma unroll
  for (int nt=0; nt<4; ++nt){
    const int gcol = 256*nt + gc1;          // gate row in [0,1024)
    const float* r0 = Whh0 + (size_t)gcol*Hdim;
    const float* r1 = Wih1 + (size_t)gcol*Hdim;
    const float* r2 = Whh1 + (size_t)gcol*Hdim;
#pragma unroll
    for (int kc=0; kc<8; ++kc){
      W1[nt][kc]  = load_wfrag(r0, 32*kc + 4*g);
      W2i[nt][kc] = load_wfrag(r1, 32*kc + 4*g);
      W2h[nt][kc] = load_wfrag(r2, 32*kc + 4*g);
    }
    bs1[nt]  = bih0[gcol] + bhh0[gcol];
    wx0v[nt] = Wih0[gcol];                  // D_IN==1 rank-1 input projection
    bs2[nt]  = bih1[gcol] + bhh1[gcol];
  }

  __syncthreads();

  float c0[4] = {0,0,0,0};
  float c1[4] = {0,0,0,0};
  int cur = 0;

  for (int t=0; t<Tdim; ++t){
    // ================= layer 1 =================
    f32x4 acc[4];
    float xv[4];
#pragma unroll
    for (int i2=0;i2<4;++i2) xv[i2] = xs[4*g + i2][t];
#pragma unroll
    for (int nt=0;nt<4;++nt){
#pragma unroll
      for (int i2=0;i2<4;++i2) acc[nt][i2] = bs1[nt] + xv[i2]*wx0v[nt];
    }
    const _Float16* hb0 = h0s + cur*(NB*Hdim);
#pragma unroll
    for (int kc=0;kc<8;++kc){
      f16x8 a = *(const f16x8*)&hb0[fidx(p,kc,g)];
#pragma unroll
      for (int nt=0;nt<4;++nt)
        acc[nt] = __builtin_amdgcn_mfma_f32_16x16x32_f16(a, W1[nt][kc], acc[nt], 0,0,0);
    }
    _Float16* hn0 = h0s + (cur^1)*(NB*Hdim);
#pragma unroll
    for (int i2=0;i2<4;++i2){
      float iv = sigm(acc[0][i2]);
      float fv = sigm(acc[1][i2]);
      float gv = tanh_fast(acc[2][i2]);
      float ov = sigm(acc[3][i2]);
      c0[i2] = fv*c0[i2] + iv*gv;
      float hv = ov*tanh_fast(c0[i2]);
      hn0[sidx(4*g+i2, gc1)] = (_Float16)hv;   // lane-local h-col, C/D row 4g+i2
    }
    __syncthreads();

    // ================= layer 2 =================
#pragma unroll
    for (int nt=0;nt<4;++nt){
#pragma unroll
      for (int i2=0;i2<4;++i2) acc[nt][i2] = bs2[nt];
    }
    // K-contribution 1: h0_new @ Wih1^T
#pragma unroll
    for (int kc=0;kc<8;++kc){
      f16x8 a = *(const f16x8*)&hn0[fidx(p,kc,g)];
#pragma unroll
      for (int nt=0;nt<4;++nt)
        acc[nt] = __builtin_amdgcn_mfma_f32_16x16x32_f16(a, W2i[nt][kc], acc[nt], 0,0,0);
    }
    // K-contribution 2: h1 @ Whh1^T
    const _Float16* hb1 = h1s + cur*(NB*Hdim);
#pragma unroll
    for (int kc=0;kc<8;++kc){
      f16x8 a = *(const f16x8*)&hb1[fidx(p,kc,g)];
#pragma unroll
      for (int nt=0;nt<4;++nt)
        acc[nt] = __builtin_amdgcn_mfma_f32_16x16x32_f16(a, W2h[nt][kc], acc[nt], 0,0,0);
    }
    _Float16* hn1 = h1s + (cur^1)*(NB*Hdim);
#pragma unroll
    for (int i2=0;i2<4;++i2){
      float iv = sigm(acc[0][i2]);
      float fv = sigm(acc[1][i2]);
      float gv = tanh_fast(acc[2][i2]);
      float ov = sigm(acc[3][i2]);
      c1[i2] = fv*c1[i2] + iv*gv;
      float hv = ov*tanh_fast(c1[i2]);
      hn1[sidx(4*g+i2, gc1)] = (_Float16)hv;
      if (t == Tdim-1) outh[4*g+i2][gc1] = hv;   // keep final h2 in fp32
    }
    __syncthreads();
    cur ^= 1;
  }

  // ---- FC epilogue: wave w reduces batch row w (out[b] = h2[b,:]@Wfc + bfc)
  float partial = 0.0f;
#pragma unroll
  for (int q=0;q<4;++q){
    int j = L + 64*q;
    partial += outh[w][j] * Wfc[j];
  }
#pragma unroll
  for (int off=32; off; off>>=1) partial += __shfl_xor(partial, off);
  if (L == 0) out[R0 + w] = partial + bfc[0];
}

extern "C" void kernel_launch(void* const* d_in, const int* in_sizes, int n_in,
                              void* d_out, int out_size, void* d_ws, size_t ws_size,
                              hipStream_t stream) {
  // setup_inputs order: x, Wih0, Whh0, bih0, bhh0, Wih1, Whh1, bih1, bhh1, Wfc, bfc
  lstm2_fused<<<dim3(Bdim/NB), dim3(1024), 0, stream>>>(
      (const float*)d_in[0],
      (const float*)d_in[1], (const float*)d_in[2],
      (const float*)d_in[3], (const float*)d_in[4],
      (const float*)d_in[5], (const float*)d_in[6],
      (const float*)d_in[7], (const float*)d_in[8],
      (const float*)d_in[9], (const float*)d_in[10],
      (float*)d_out);
}

// Round 2
// 23327.818 us; speedup vs baseline: 1.0033x; 1.0033x over previous
//
#include <hip/hip_runtime.h>

// 2-layer LSTM (H=256, B=512, T=512, D_IN=1) + FC, multi-CU weight-resident.
//
// Round-1 lesson: per-CU register file is 512 KB; 1.5 MB of f16 weights can't
// live on one CU. Design: 32 batch-groups x 4 gate-split blocks = 128 blocks
// of 256 threads (4 waves, 1 wave/SIMD, <=512 VGPR). Block j of a group owns
// h-columns [64j,64j+64) of BOTH layers:
//   Whh0, Wih1 slices -> registers (256 VGPR/lane), Whh1 slice -> LDS (128 KB).
// h0/h1 are exchanged via double-buffered global buffers in d_ws (f16, stored
// in MFMA-fragment-permuted order so A-frags are 16B contiguous loads).
// Per-phase sync: split monotonic arrival counters (cntA: h0 ready, cntB: h1
// ready), device-scope release/acquire. Phase t computes L1(t) and L2(t-1).
// Co-residency: 128 blocks, 1 block/CU forced by VGPR+LDS -> all resident.

#define Hdim 256
#define Tdim 512
#define NB 16
#define NGRP 32

typedef float f32x4 __attribute__((ext_vector_type(4)));
typedef _Float16 f16x8 __attribute__((ext_vector_type(8)));

// ws layout (bytes):
//   [0, 4096)              : counters, grp g: cntA at g*128, cntB at g*128+64
//   [4096, 4096+524288)    : h0_ex  [2 parity][32 grp][16 row][256 pos] f16
//   [528384, +524288)      : h1_ex  same shape
#define CNT_BYTES 4096
#define H0_OFF 4096
#define EXPAR (NGRP * NB * Hdim)          // f16 elems per parity buffer
#define H1_OFF (H0_OFF + 2 * EXPAR * 2)   // bytes

__device__ __forceinline__ float sigm(float x){ return 1.0f/(1.0f + __expf(-x)); }
__device__ __forceinline__ float tanh_fast(float x){
  float ax = fabsf(x);
  float e = __expf(-2.0f*ax);
  float r = (1.0f - e)/(1.0f + e);
  return copysignf(r, x);
}

// position permutation: h stored at [row][pcol(k)] so that a contiguous 8-f16
// read at pos 32*kc+8*g delivers logical k = 32kc+4g+{0..3,16..19} (validated
// round 1: matches load_wfrag's B-operand k-mapping; A/B consistency is what
// matters, C/D mapping is HW-verified).
__device__ __forceinline__ int pcol(int k){
  return (k&3) | (((k>>4)&1)<<2) | (((k>>2)&3)<<3) | ((k>>5)<<5);
}

__device__ __forceinline__ f16x8 load_wfrag(const float* Wrow, int k0){
  float4 a = *(const float4*)(Wrow + k0);
  float4 b = *(const float4*)(Wrow + k0 + 16);
  f16x8 r;
  r[0]=(_Float16)a.x; r[1]=(_Float16)a.y; r[2]=(_Float16)a.z; r[3]=(_Float16)a.w;
  r[4]=(_Float16)b.x; r[5]=(_Float16)b.y; r[6]=(_Float16)b.z; r[7]=(_Float16)b.w;
  return r;
}

__device__ __forceinline__ unsigned ld_acq(const unsigned* p){
  return __hip_atomic_load(p, __ATOMIC_ACQUIRE, __HIP_MEMORY_SCOPE_AGENT);
}
__device__ __forceinline__ void spin_ge(const unsigned* p, unsigned tgt){
  long it = 0;
  while (ld_acq(p) < tgt){ if (++it > 20000000L) break; }  // bounded: no hang on bug
}

__global__ __launch_bounds__(256, 1) void lstm2_mc(
    const float* __restrict__ x,
    const float* __restrict__ Wih0, const float* __restrict__ Whh0,
    const float* __restrict__ bih0, const float* __restrict__ bhh0,
    const float* __restrict__ Wih1, const float* __restrict__ Whh1,
    const float* __restrict__ bih1, const float* __restrict__ bhh1,
    const float* __restrict__ Wfc,  const float* __restrict__ bfc,
    float* __restrict__ out, unsigned char* __restrict__ ws)
{
  // Whh1 slice in fragment order: [wave][gate][kc][lane] of f16x8 = 128 KB
  __shared__ f16x8 w2h_lds[4*4*8*64];

  const int b   = blockIdx.x;
  const int xcd = b & 7;            // XCD-aware grouping: 4 members share an XCD
  const int slot= b >> 3;
  const int j   = slot & 3;         // group member: owns h-cols [64j, 64j+64)
  const int grp = xcd*4 + (slot>>2);
  const int tid = threadIdx.x;
  const int w   = tid >> 6;         // wave 0..3: owns cols 64j+16w+p, all 4 gates
  const int L   = tid & 63;
  const int p   = L & 15;
  const int gq  = L >> 4;
  const int R0  = grp * NB;

  unsigned* cntA = (unsigned*)(ws + (size_t)grp*128);
  unsigned* cntB = (unsigned*)(ws + (size_t)grp*128 + 64);
  _Float16* h0x = (_Float16*)(ws + H0_OFF);
  _Float16* h1x = (_Float16*)(ws + H1_OFF);

  // ---- weights: Whh0, Wih1 -> registers; Whh1 -> LDS (frag order)
  f16x8 W1[4][8], W2i[4][8];
  float bs1[4], wx0[4], bs2[4];
#pragma unroll
  for (int gate=0; gate<4; ++gate){
    const int gr = 256*gate + 64*j + 16*w + p;   // gate row in [0,1024)
    const float* r0 = Whh0 + (size_t)gr*Hdim;
    const float* r1 = Wih1 + (size_t)gr*Hdim;
    const float* r2 = Whh1 + (size_t)gr*Hdim;
#pragma unroll
    for (int kc=0; kc<8; ++kc){
      W1[gate][kc]  = load_wfrag(r0, 32*kc + 4*gq);
      W2i[gate][kc] = load_wfrag(r1, 32*kc + 4*gq);
      w2h_lds[((w*4+gate)*8+kc)*64 + L] = load_wfrag(r2, 32*kc + 4*gq);
    }
    bs1[gate] = bih0[gr] + bhh0[gr];
    wx0[gate] = Wih0[gr];
    bs2[gate] = bih1[gr] + bhh1[gr];
  }
  // no __syncthreads needed: each wave reads only its own w2h_lds region

  const int myq = pcol(64*j + 16*w + p);   // store position for this lane's h-col
  float c0[4] = {0,0,0,0};
  float c1[4] = {0,0,0,0};

  for (int t=0; t<=Tdim; ++t){
    // ---- wait for h0(t-1) from all group members, then load A-frags
    f16x8 a0[8];
    if (t){
      spin_ge(cntA, 16u*(unsigned)t);
      const _Float16* src = h0x + (size_t)((t-1)&1)*EXPAR + grp*(NB*Hdim) + p*Hdim + 8*gq;
#pragma unroll
      for (int kc=0; kc<8; ++kc) a0[kc] = *(const f16x8*)(src + 32*kc);
    }

    // ================= layer 1, step t =================
    if (t < Tdim){
      float xv[4];
#pragma unroll
      for (int u=0; u<4; ++u) xv[u] = x[(size_t)(R0 + 4*gq + u)*Tdim + t];
      f32x4 acc[4];
#pragma unroll
      for (int gate=0; gate<4; ++gate)
#pragma unroll
        for (int u=0; u<4; ++u) acc[gate][u] = bs1[gate] + xv[u]*wx0[gate];
      if (t){
#pragma unroll
        for (int kc=0; kc<8; ++kc)
#pragma unroll
          for (int gate=0; gate<4; ++gate)
            acc[gate] = __builtin_amdgcn_mfma_f32_16x16x32_f16(a0[kc], W1[gate][kc], acc[gate], 0,0,0);
      }
      _Float16* dst = h0x + (size_t)(t&1)*EXPAR + grp*(NB*Hdim) + myq;
#pragma unroll
      for (int u=0; u<4; ++u){
        float iv = sigm(acc[0][u]);
        float fv = sigm(acc[1][u]);
        float gv = tanh_fast(acc[2][u]);
        float ov = sigm(acc[3][u]);
        c0[u] = fv*c0[u] + iv*gv;
        dst[(4*gq+u)*Hdim] = (_Float16)(ov*tanh_fast(c0[u]));
      }
      // close the h0 recurrence cycle ASAP (L2 work rides behind this arrival)
      __threadfence();
      if (L == 0) __hip_atomic_fetch_add(cntA, 1u, __ATOMIC_RELEASE, __HIP_MEMORY_SCOPE_AGENT);
    } else {
      __threadfence();
      if (L == 0) __hip_atomic_fetch_add(cntA, 1u, __ATOMIC_RELEASE, __HIP_MEMORY_SCOPE_AGENT);
    }

    // ================= layer 2, step t-1 =================
    if (t){
      f16x8 a1[8];
      const bool has_h1 = (t > 1);
      if (has_h1){
        spin_ge(cntB, 16u*(unsigned)t);   // h1(t-2) written during phase t-1
        const _Float16* src1 = h1x + (size_t)(t&1)*EXPAR + grp*(NB*Hdim) + p*Hdim + 8*gq;
#pragma unroll
        for (int kc=0; kc<8; ++kc) a1[kc] = *(const f16x8*)(src1 + 32*kc);
      }
      f32x4 acc[4];
#pragma unroll
      for (int gate=0; gate<4; ++gate)
#pragma unroll
        for (int u=0; u<4; ++u) acc[gate][u] = bs2[gate];
      // input contribution: h0(t-1) @ Wih1^T (reuses a0 frags)
#pragma unroll
      for (int kc=0; kc<8; ++kc)
#pragma unroll
        for (int gate=0; gate<4; ++gate)
          acc[gate] = __builtin_amdgcn_mfma_f32_16x16x32_f16(a0[kc], W2i[gate][kc], acc[gate], 0,0,0);
      // recurrent contribution: h1(t-2) @ Whh1^T (B-frags from LDS)
      if (has_h1){
#pragma unroll
        for (int kc=0; kc<8; ++kc)
#pragma unroll
          for (int gate=0; gate<4; ++gate){
            f16x8 wf = w2h_lds[((w*4+gate)*8+kc)*64 + L];
            acc[gate] = __builtin_amdgcn_mfma_f32_16x16x32_f16(a1[kc], wf, acc[gate], 0,0,0);
          }
      }
      _Float16* dst1 = h1x + (size_t)((t-1)&1)*EXPAR + grp*(NB*Hdim) + myq;
#pragma unroll
      for (int u=0; u<4; ++u){
        float iv = sigm(acc[0][u]);
        float fv = sigm(acc[1][u]);
        float gv = tanh_fast(acc[2][u]);
        float ov = sigm(acc[3][u]);
        c1[u] = fv*c1[u] + iv*gv;
        dst1[(4*gq+u)*Hdim] = (_Float16)(ov*tanh_fast(c1[u]));
      }
    }
    __threadfence();
    if (L == 0) __hip_atomic_fetch_add(cntB, 1u, __ATOMIC_RELEASE, __HIP_MEMORY_SCOPE_AGENT);
  }

  // ---- FC epilogue: member 0 of each group reduces its 16 batch rows
  spin_ge(cntB, 16u*(unsigned)(Tdim+1));
  if (j == 0){
    const _Float16* hsrc = h1x + (size_t)((Tdim-1)&1)*EXPAR + grp*(NB*Hdim);
    const float bfc0 = bfc[0];
#pragma unroll
    for (int u=0; u<4; ++u){
      const int r = 4*w + u;
      float s = 0.0f;
#pragma unroll
      for (int q4=0; q4<4; ++q4){
        int q = L + 64*q4;
        // inverse of pcol: logical k for stored position q
        int k = (q&3) | (((q>>3)&3)<<2) | (((q>>2)&1)<<4) | ((q>>5)<<5);
        s += (float)hsrc[r*Hdim + q] * Wfc[k];
      }
#pragma unroll
      for (int off=32; off; off>>=1) s += __shfl_xor(s, off);
      if (L == 0) out[R0 + r] = s + bfc0;
    }
  }
}

extern "C" void kernel_launch(void* const* d_in, const int* in_sizes, int n_in,
                              void* d_out, int out_size, void* d_ws, size_t ws_size,
                              hipStream_t stream) {
  // zero the arrival counters (ws is poisoned 0xAA before every launch)
  hipMemsetAsync(d_ws, 0, CNT_BYTES, stream);
  lstm2_mc<<<dim3(128), dim3(256), 0, stream>>>(
      (const float*)d_in[0],
      (const float*)d_in[1], (const float*)d_in[2],
      (const float*)d_in[3], (const float*)d_in[4],
      (const float*)d_in[5], (const float*)d_in[6],
      (const float*)d_in[7], (const float*)d_in[8],
      (const float*)d_in[9], (const float*)d_in[10],
      (float*)d_out, (unsigned char*)d_ws);
}

// Round 3
// 3873.603 us; speedup vs baseline: 6.0421x; 6.0223x over previous
//
#include <hip/hip_runtime.h>

// 2-layer LSTM (H=256, B=512, T=512) + FC. 32 batch-groups x 4 gate-split
// blocks (128 CUs). Weights register/LDS-resident as round 2 (validated).
//
// Round-2 lesson: fence+flag sync across XCDs costs ~45us/phase (agent
// release fences emit L2 writebacks; acquire spins emit invalidates).
// Round-3: FENCE-FREE exchange. Each exchanged dword = (tag(step)<<16) |
// f16(h). Writers: relaxed agent-scope atomic stores (write-through to MALL,
// no cache maintenance). Readers: global_load_dwordx4 sc0 sc1 (bypass
// L1/L2), validate every epoch, retry until match. Mod-3 ring buffers:
// data deps bound drift to +-1 phase, so 3 slots are provably
// overwrite-safe. No fences, no barriers, no counters. Poison 0xAAAA can't
// alias a tag (tags <= 512).

#define Hdim 256
#define Tdim 512
#define NB 16
#define NGRP 32

typedef float f32x4 __attribute__((ext_vector_type(4)));
typedef _Float16 f16x8 __attribute__((ext_vector_type(8)));

#define SLOTD (NGRP * NB * 256)        // dwords per ring slot (512 KB)
#define TAGOF(s) ((unsigned)((s) + 1)) // tag of step s (>=1, <=512)

__device__ __forceinline__ float sigm(float x){ return 1.0f/(1.0f + __expf(-x)); }
__device__ __forceinline__ float tanh_fast(float x){
  float ax = fabsf(x);
  float e = __expf(-2.0f*ax);
  float r = (1.0f - e)/(1.0f + e);
  return copysignf(r, x);
}

// h position permutation (validated rounds 1-2): contiguous 8 positions at
// 32*kc+8*gq hold logical k = 32kc+4gq+{0..3,16..19} = one A/B fragment.
__device__ __forceinline__ int pcol(int k){
  return (k&3) | (((k>>4)&1)<<2) | (((k>>2)&3)<<3) | ((k>>5)<<5);
}

__device__ __forceinline__ f16x8 load_wfrag(const float* Wrow, int k0){
  float4 a = *(const float4*)(Wrow + k0);
  float4 b = *(const float4*)(Wrow + k0 + 16);
  f16x8 r;
  r[0]=(_Float16)a.x; r[1]=(_Float16)a.y; r[2]=(_Float16)a.z; r[3]=(_Float16)a.w;
  r[4]=(_Float16)b.x; r[5]=(_Float16)b.y; r[6]=(_Float16)b.z; r[7]=(_Float16)b.w;
  return r;
}

// relaxed agent-scope atomic store: write-through to device coherence point
__device__ __forceinline__ void st_mall(unsigned* p, unsigned v){
  __hip_atomic_store(p, v, __ATOMIC_RELAXED, __HIP_MEMORY_SCOPE_AGENT);
}
__device__ __forceinline__ unsigned ld_mall(const unsigned* p){
  return __hip_atomic_load(p, __ATOMIC_RELAXED, __HIP_MEMORY_SCOPE_AGENT);
}

// Read 8 epoch-tagged fragments (64 dwords) for this lane; returns true iff
// every word carried the expected tag. out[] is filled unconditionally so a
// bounded-retry exhaustion degrades to wrong data, never UB/hang.
__device__ __forceinline__ bool try_read_frags(const unsigned* base, unsigned tag, f16x8* out){
  uint4 ra[8], rb[8];
#pragma unroll
  for (int kc=0; kc<8; ++kc){
    const unsigned* pp = base + 32*kc;
    asm volatile("global_load_dwordx4 %0, %1, off sc0 sc1" : "=v"(ra[kc]) : "v"(pp));
    asm volatile("global_load_dwordx4 %0, %1, off sc0 sc1" : "=v"(rb[kc]) : "v"(pp+4));
  }
  asm volatile("s_waitcnt vmcnt(0)" ::: "memory");
  __builtin_amdgcn_sched_barrier(0);   // rule #18: pin consumers below the wait
  unsigned bad = 0;
#pragma unroll
  for (int kc=0; kc<8; ++kc){
    bad |= ((ra[kc].x>>16)^tag) | ((ra[kc].y>>16)^tag) | ((ra[kc].z>>16)^tag) | ((ra[kc].w>>16)^tag)
         | ((rb[kc].x>>16)^tag) | ((rb[kc].y>>16)^tag) | ((rb[kc].z>>16)^tag) | ((rb[kc].w>>16)^tag);
    uint4 pk;
    pk.x = (ra[kc].x & 0xffffu) | (ra[kc].y << 16);
    pk.y = (ra[kc].z & 0xffffu) | (ra[kc].w << 16);
    pk.z = (rb[kc].x & 0xffffu) | (rb[kc].y << 16);
    pk.w = (rb[kc].z & 0xffffu) | (rb[kc].w << 16);
    out[kc] = __builtin_bit_cast(f16x8, pk);
  }
  return !__any((int)bad);
}

__global__ __launch_bounds__(256, 1) void lstm2_ef(
    const float* __restrict__ x,
    const float* __restrict__ Wih0, const float* __restrict__ Whh0,
    const float* __restrict__ bih0, const float* __restrict__ bhh0,
    const float* __restrict__ Wih1, const float* __restrict__ Whh1,
    const float* __restrict__ bih1, const float* __restrict__ bhh1,
    const float* __restrict__ Wfc,  const float* __restrict__ bfc,
    float* __restrict__ out, unsigned* __restrict__ ws)
{
  __shared__ f16x8 w2h_lds[4*4*8*64];   // Whh1 slice, frag order, 128 KB

  const int b   = blockIdx.x;
  const int j   = b & 3;                // group member: h-cols [64j, 64j+64)
  const int grp = b >> 2;
  const int tid = threadIdx.x;
  const int w   = tid >> 6;
  const int L   = tid & 63;
  const int p   = L & 15;
  const int gq  = L >> 4;
  const int R0  = grp * NB;

  unsigned* h0r = ws;                   // [3][NGRP][NB][256] dwords
  unsigned* h1r = ws + 3*(size_t)SLOTD;

  // ---- weights: Whh0, Wih1 -> registers; Whh1 -> LDS (validated round 2)
  f16x8 W1[4][8], W2i[4][8];
  float bs1[4], wx0[4], bs2[4];
#pragma unroll
  for (int gate=0; gate<4; ++gate){
    const int gr = 256*gate + 64*j + 16*w + p;
    const float* r0 = Whh0 + (size_t)gr*Hdim;
    const float* r1 = Wih1 + (size_t)gr*Hdim;
    const float* r2 = Whh1 + (size_t)gr*Hdim;
#pragma unroll
    for (int kc=0; kc<8; ++kc){
      W1[gate][kc]  = load_wfrag(r0, 32*kc + 4*gq);
      W2i[gate][kc] = load_wfrag(r1, 32*kc + 4*gq);
      w2h_lds[((w*4+gate)*8+kc)*64 + L] = load_wfrag(r2, 32*kc + 4*gq);
    }
    bs1[gate] = bih0[gr] + bhh0[gr];
    wx0[gate] = Wih0[gr];
    bs2[gate] = bih1[gr] + bhh1[gr];
  }
  // each wave reads only its own w2h_lds region: no barrier needed

  const int myq = pcol(64*j + 16*w + p);
  const int grpoff = grp * (NB*256);
  float c0[4] = {0,0,0,0};
  float c1[4] = {0,0,0,0};

  for (int t=0; t<=Tdim; ++t){
    // ---- h0(t-1) fragments (needed by L1(t) and L2(t-1))
    f16x8 a0[8];
    if (t){
      const unsigned* src = h0r + (size_t)((t-1)%3)*SLOTD + grpoff + p*256 + 8*gq;
      long it = 0; bool ok;
      do { ok = try_read_frags(src, TAGOF(t-1), a0); } while (!ok && ++it < 60000);
    }

    // ================= layer 1, step t =================
    if (t < Tdim){
      float xv[4];
#pragma unroll
      for (int u=0; u<4; ++u) xv[u] = x[(size_t)(R0 + 4*gq + u)*Tdim + t];
      f32x4 acc[4];
#pragma unroll
      for (int gate=0; gate<4; ++gate)
#pragma unroll
        for (int u=0; u<4; ++u) acc[gate][u] = bs1[gate] + xv[u]*wx0[gate];
      if (t){
#pragma unroll
        for (int kc=0; kc<8; ++kc)
#pragma unroll
          for (int gate=0; gate<4; ++gate)
            acc[gate] = __builtin_amdgcn_mfma_f32_16x16x32_f16(a0[kc], W1[gate][kc], acc[gate], 0,0,0);
      }
      unsigned* dst = h0r + (size_t)(t%3)*SLOTD + grpoff + myq;
      const unsigned tg = TAGOF(t) << 16;
#pragma unroll
      for (int u=0; u<4; ++u){
        float iv = sigm(acc[0][u]);
        float fv = sigm(acc[1][u]);
        float gv = tanh_fast(acc[2][u]);
        float ov = sigm(acc[3][u]);
        c0[u] = fv*c0[u] + iv*gv;
        unsigned short hb = __builtin_bit_cast(unsigned short, (_Float16)(ov*tanh_fast(c0[u])));
        st_mall(&dst[(4*gq+u)*256], tg | hb);
      }
    }

    // ================= layer 2, step t-1 =================
    if (t){
      f16x8 a1[8];
      const bool has_h1 = (t > 1);
      if (has_h1){
        const unsigned* src1 = h1r + (size_t)((t-2)%3)*SLOTD + grpoff + p*256 + 8*gq;
        long it = 0; bool ok;
        do { ok = try_read_frags(src1, TAGOF(t-2), a1); } while (!ok && ++it < 60000);
      }
      f32x4 acc[4];
#pragma unroll
      for (int gate=0; gate<4; ++gate)
#pragma unroll
        for (int u=0; u<4; ++u) acc[gate][u] = bs2[gate];
#pragma unroll
      for (int kc=0; kc<8; ++kc)
#pragma unroll
        for (int gate=0; gate<4; ++gate)
          acc[gate] = __builtin_amdgcn_mfma_f32_16x16x32_f16(a0[kc], W2i[gate][kc], acc[gate], 0,0,0);
      if (has_h1){
#pragma unroll
        for (int kc=0; kc<8; ++kc)
#pragma unroll
          for (int gate=0; gate<4; ++gate){
            f16x8 wf = w2h_lds[((w*4+gate)*8+kc)*64 + L];
            acc[gate] = __builtin_amdgcn_mfma_f32_16x16x32_f16(a1[kc], wf, acc[gate], 0,0,0);
          }
      }
      unsigned* dst1 = h1r + (size_t)((t-1)%3)*SLOTD + grpoff + myq;
      const unsigned tg1 = TAGOF(t-1) << 16;
#pragma unroll
      for (int u=0; u<4; ++u){
        float iv = sigm(acc[0][u]);
        float fv = sigm(acc[1][u]);
        float gv = tanh_fast(acc[2][u]);
        float ov = sigm(acc[3][u]);
        c1[u] = fv*c1[u] + iv*gv;
        unsigned short hb = __builtin_bit_cast(unsigned short, (_Float16)(ov*tanh_fast(c1[u])));
        st_mall(&dst1[(4*gq+u)*256], tg1 | hb);
      }
    }
  }

  // ---- FC epilogue: member 0 of each group reduces its 16 batch rows
  if (j == 0){
    const unsigned* hsrc = h1r + (size_t)((Tdim-1)%3)*SLOTD + grpoff;
    const float bfc0 = bfc[0];
    const unsigned want = TAGOF(Tdim-1);
#pragma unroll
    for (int u=0; u<4; ++u){
      const int r = 4*w + u;
      float s = 0.0f;
#pragma unroll
      for (int q4=0; q4<4; ++q4){
        int q = L + 64*q4;
        unsigned v; long it = 0;
        do { v = ld_mall(&hsrc[r*256 + q]); } while ((v>>16) != want && ++it < 60000);
        int k = (q&3) | (((q>>3)&3)<<2) | (((q>>2)&1)<<4) | ((q>>5)<<5);  // pcol^-1
        s += (float)__builtin_bit_cast(_Float16, (unsigned short)(v & 0xffffu)) * Wfc[k];
      }
#pragma unroll
      for (int off=32; off; off>>=1) s += __shfl_xor(s, off);
      if (L == 0) out[R0 + r] = s + bfc0;
    }
  }
}

extern "C" void kernel_launch(void* const* d_in, const int* in_sizes, int n_in,
                              void* d_out, int out_size, void* d_ws, size_t ws_size,
                              hipStream_t stream) {
  // no counters, no memset: harness re-poisons ws to 0xAA (tag 0xAAAA never
  // matches a real tag <= 512)
  lstm2_ef<<<dim3(128), dim3(256), 0, stream>>>(
      (const float*)d_in[0],
      (const float*)d_in[1], (const float*)d_in[2],
      (const float*)d_in[3], (const float*)d_in[4],
      (const float*)d_in[5], (const float*)d_in[6],
      (const float*)d_in[7], (const float*)d_in[8],
      (const float*)d_in[9], (const float*)d_in[10],
      (float*)d_out, (unsigned*)d_ws);
}